// Round 6
// baseline (1872.775 us; speedup 1.0000x reference)
//
#include <hip/hip_runtime.h>
#include <hip/hip_bf16.h>

#define EPS 1e-5f

typedef short bf16x8 __attribute__((ext_vector_type(8)));
typedef short short4v __attribute__((ext_vector_type(4)));
typedef float f32x4 __attribute__((ext_vector_type(4)));

static __device__ __forceinline__ short f2bf(float x) {
    __hip_bfloat16 h = __float2bfloat16(x);
    return *reinterpret_cast<short*>(&h);
}
static __device__ __forceinline__ float bf2f(short x) {
    __hip_bfloat16 h;
    *reinterpret_cast<short*>(&h) = x;
    return __bfloat162float(h);
}

// ========== split-bf16 MFMA GEMM: C = act(A[M,K](f32) @ BT[N,K]^T + bias) ==========
// SPLIT=3: A hi/lo, B hi/lo. OUTM: 0=f32, 1=bf16, 2=bf16 hi/lo pair (Cout,Cout2)
template<int SPLIT, int ACT, int OUTM>
__global__ __launch_bounds__(256) void gemm_split(const float* __restrict__ A,
                                                  const short* __restrict__ BTh,
                                                  const short* __restrict__ BTl,
                                                  const float* __restrict__ bias,
                                                  void* __restrict__ Cout,
                                                  void* __restrict__ Cout2,
                                                  int M, int N, int K) {
    __shared__ short Ah[128][40];
    __shared__ short Al[128][40];
    __shared__ short Bh[128][40];
    __shared__ short Bl[128][40];
    const int tid = threadIdx.x;
    const int row0 = blockIdx.y * 128, col0 = blockIdx.x * 128;
    const int lane = tid & 63, w = tid >> 6;
    const int wr = w >> 1, wc = w & 1;
    const int lr = lane & 15, lg = lane >> 4;
    f32x4 acc[4][4] = {};

    for (int k0 = 0; k0 < K; k0 += 32) {
        #pragma unroll
        for (int i = 0; i < 4; ++i) {
            int idx = i * 256 + tid;
            int r = idx >> 3, q = idx & 7;
            int gr = row0 + r, gk = k0 + q * 4;
            f32x4 v;
            if (gr < M && gk + 3 < K) {
                v = *reinterpret_cast<const f32x4*>(&A[(size_t)gr * K + gk]);
            } else {
                #pragma unroll
                for (int j = 0; j < 4; ++j)
                    v[j] = (gr < M && gk + j < K) ? A[(size_t)gr * K + gk + j] : 0.f;
            }
            short4v h, l;
            #pragma unroll
            for (int j = 0; j < 4; ++j) {
                h[j] = f2bf(v[j]);
                l[j] = f2bf(v[j] - bf2f(h[j]));
            }
            *reinterpret_cast<short4v*>(&Ah[r][q * 4]) = h;
            *reinterpret_cast<short4v*>(&Al[r][q * 4]) = l;
        }
        #pragma unroll
        for (int i = 0; i < 4; ++i) {
            int idx = i * 256 + tid;
            int r = idx >> 3, q = idx & 7;
            int gc = col0 + r, gk = k0 + q * 4;
            short4v u, ul;
            if (gk + 3 < K) {
                u = *reinterpret_cast<const short4v*>(&BTh[(size_t)gc * K + gk]);
                if (SPLIT == 3) ul = *reinterpret_cast<const short4v*>(&BTl[(size_t)gc * K + gk]);
            } else {
                #pragma unroll
                for (int j = 0; j < 4; ++j) {
                    u[j] = (gk + j < K) ? BTh[(size_t)gc * K + gk + j] : (short)0;
                    if (SPLIT == 3) ul[j] = (gk + j < K) ? BTl[(size_t)gc * K + gk + j] : (short)0;
                }
            }
            *reinterpret_cast<short4v*>(&Bh[r][q * 4]) = u;
            if (SPLIT == 3) *reinterpret_cast<short4v*>(&Bl[r][q * 4]) = ul;
        }
        __syncthreads();
        bf16x8 afh[4], afl[4], bfh[4];
        #pragma unroll
        for (int mi = 0; mi < 4; ++mi) {
            afh[mi] = *reinterpret_cast<const bf16x8*>(&Ah[wr * 64 + mi * 16 + lr][lg * 8]);
            afl[mi] = *reinterpret_cast<const bf16x8*>(&Al[wr * 64 + mi * 16 + lr][lg * 8]);
        }
        #pragma unroll
        for (int ni = 0; ni < 4; ++ni)
            bfh[ni] = *reinterpret_cast<const bf16x8*>(&Bh[wc * 64 + ni * 16 + lr][lg * 8]);
        #pragma unroll
        for (int mi = 0; mi < 4; ++mi)
            #pragma unroll
            for (int ni = 0; ni < 4; ++ni) {
                acc[mi][ni] = __builtin_amdgcn_mfma_f32_16x16x32_bf16(afh[mi], bfh[ni], acc[mi][ni], 0, 0, 0);
                acc[mi][ni] = __builtin_amdgcn_mfma_f32_16x16x32_bf16(afl[mi], bfh[ni], acc[mi][ni], 0, 0, 0);
            }
        if (SPLIT == 3) {
            bf16x8 bfl[4];
            #pragma unroll
            for (int ni = 0; ni < 4; ++ni)
                bfl[ni] = *reinterpret_cast<const bf16x8*>(&Bl[wc * 64 + ni * 16 + lr][lg * 8]);
            #pragma unroll
            for (int mi = 0; mi < 4; ++mi)
                #pragma unroll
                for (int ni = 0; ni < 4; ++ni)
                    acc[mi][ni] = __builtin_amdgcn_mfma_f32_16x16x32_bf16(afh[mi], bfl[ni], acc[mi][ni], 0, 0, 0);
        }
        __syncthreads();
    }

    #pragma unroll
    for (int mi = 0; mi < 4; ++mi) {
        #pragma unroll
        for (int ni = 0; ni < 4; ++ni) {
            int col = col0 + wc * 64 + ni * 16 + lr;
            float bv = bias ? bias[col] : 0.f;
            #pragma unroll
            for (int r = 0; r < 4; ++r) {
                int row = row0 + wr * 64 + mi * 16 + lg * 4 + r;
                if (row >= M) continue;
                float v = acc[mi][ni][r] + bv;
                if (ACT) v = fmaxf(v, 0.f);
                if (OUTM == 0) ((float*)Cout)[(size_t)row * N + col] = v;
                else if (OUTM == 1) ((short*)Cout)[(size_t)row * N + col] = f2bf(v);
                else {
                    short h = f2bf(v);
                    ((short*)Cout)[(size_t)row * N + col] = h;
                    ((short*)Cout2)[(size_t)row * N + col] = f2bf(v - bf2f(h));
                }
            }
        }
    }
}

// ========== plain bf16 GEMM (tolerant path: ep projection) ==========
template<int ACT, int OUTBF>
__global__ __launch_bounds__(256) void gemm_bf16(const short* __restrict__ A,
                                                 const short* __restrict__ BT,
                                                 const float* __restrict__ bias,
                                                 void* __restrict__ Cout,
                                                 int M, int N, int K) {
    __shared__ short As[128][40];
    __shared__ short Bs[128][40];
    const int tid = threadIdx.x;
    const int row0 = blockIdx.y * 128, col0 = blockIdx.x * 128;
    const int lane = tid & 63, w = tid >> 6;
    const int wr = w >> 1, wc = w & 1;
    const int lr = lane & 15, lg = lane >> 4;
    f32x4 acc[4][4] = {};

    for (int k0 = 0; k0 < K; k0 += 32) {
        #pragma unroll
        for (int i = 0; i < 4; ++i) {
            int idx = i * 256 + tid;
            int r = idx >> 3, q = idx & 7;
            int gk = k0 + q * 4;
            int gr = row0 + r;
            short4v v;
            if (gr < M && gk + 3 < K) {
                v = *reinterpret_cast<const short4v*>(&A[(size_t)gr * K + gk]);
            } else {
                #pragma unroll
                for (int j = 0; j < 4; ++j)
                    v[j] = (gr < M && gk + j < K) ? A[(size_t)gr * K + gk + j] : (short)0;
            }
            *reinterpret_cast<short4v*>(&As[r][q * 4]) = v;
            int gc = col0 + r;
            short4v u;
            if (gc < N && gk + 3 < K) {
                u = *reinterpret_cast<const short4v*>(&BT[(size_t)gc * K + gk]);
            } else {
                #pragma unroll
                for (int j = 0; j < 4; ++j)
                    u[j] = (gc < N && gk + j < K) ? BT[(size_t)gc * K + gk + j] : (short)0;
            }
            *reinterpret_cast<short4v*>(&Bs[r][q * 4]) = u;
        }
        __syncthreads();
        bf16x8 af[4], bfr[4];
        #pragma unroll
        for (int mi = 0; mi < 4; ++mi)
            af[mi] = *reinterpret_cast<const bf16x8*>(&As[wr * 64 + mi * 16 + lr][lg * 8]);
        #pragma unroll
        for (int ni = 0; ni < 4; ++ni)
            bfr[ni] = *reinterpret_cast<const bf16x8*>(&Bs[wc * 64 + ni * 16 + lr][lg * 8]);
        #pragma unroll
        for (int mi = 0; mi < 4; ++mi)
            #pragma unroll
            for (int ni = 0; ni < 4; ++ni)
                acc[mi][ni] = __builtin_amdgcn_mfma_f32_16x16x32_bf16(af[mi], bfr[ni], acc[mi][ni], 0, 0, 0);
        __syncthreads();
    }

    #pragma unroll
    for (int mi = 0; mi < 4; ++mi) {
        #pragma unroll
        for (int ni = 0; ni < 4; ++ni) {
            int col = col0 + wc * 64 + ni * 16 + lr;
            float bv = bias ? bias[col] : 0.f;
            #pragma unroll
            for (int r = 0; r < 4; ++r) {
                int row = row0 + wr * 64 + mi * 16 + lg * 4 + r;
                if (row >= M) continue;
                float v = acc[mi][ni][r] + bv;
                if (ACT) v = fmaxf(v, 0.f);
                if (OUTBF) ((short*)Cout)[(size_t)row * N + col] = f2bf(v);
                else       ((float*)Cout)[(size_t)row * N + col] = v;
            }
        }
    }
}

// ========== Y GEMM: Y'[M,1024] = (xph+xpl)[M,128] @ wbH[1024,128]^T + Wl1-colbias ==========
__global__ __launch_bounds__(256) void gemm_y(const short* __restrict__ xph,
                                              const short* __restrict__ xpl,
                                              const short* __restrict__ BT,
                                              const float* __restrict__ wl1,  // [128][8] (d*8+s)
                                              short* __restrict__ Y, int M) {
    __shared__ short Ah[128][136];
    __shared__ short Al[128][136];
    const int tid = threadIdx.x;
    const int row0 = blockIdx.x * 128;
    const int lane = tid & 63, w = tid >> 6;
    const int wr = w >> 1, wc = w & 1;
    const int lr = lane & 15, lg = lane >> 4;

    #pragma unroll
    for (int i = 0; i < 8; ++i) {
        int idx = i * 256 + tid;
        int r = idx >> 4, q = idx & 15;
        int gr = row0 + r;
        bf16x8 vh, vl;
        if (gr < M) {
            vh = *reinterpret_cast<const bf16x8*>(&xph[(size_t)gr * 128 + q * 8]);
            vl = *reinterpret_cast<const bf16x8*>(&xpl[(size_t)gr * 128 + q * 8]);
        } else {
            #pragma unroll
            for (int j = 0; j < 8; ++j) { vh[j] = 0; vl[j] = 0; }
        }
        *reinterpret_cast<bf16x8*>(&Ah[r][q * 8]) = vh;
        *reinterpret_cast<bf16x8*>(&Al[r][q * 8]) = vl;
    }
    __syncthreads();

    for (int ct = 0; ct < 8; ++ct) {
        f32x4 acc[4][4] = {};
        #pragma unroll
        for (int k = 0; k < 4; ++k) {
            bf16x8 bfr[4];
            #pragma unroll
            for (int ni = 0; ni < 4; ++ni) {
                int col = ct * 128 + wc * 64 + ni * 16 + lr;
                bfr[ni] = *reinterpret_cast<const bf16x8*>(&BT[(size_t)col * 128 + k * 32 + lg * 8]);
            }
            bf16x8 ah[4], al[4];
            #pragma unroll
            for (int mi = 0; mi < 4; ++mi) {
                ah[mi] = *reinterpret_cast<const bf16x8*>(&Ah[wr * 64 + mi * 16 + lr][k * 32 + lg * 8]);
                al[mi] = *reinterpret_cast<const bf16x8*>(&Al[wr * 64 + mi * 16 + lr][k * 32 + lg * 8]);
            }
            #pragma unroll
            for (int mi = 0; mi < 4; ++mi)
                #pragma unroll
                for (int ni = 0; ni < 4; ++ni) {
                    acc[mi][ni] = __builtin_amdgcn_mfma_f32_16x16x32_bf16(ah[mi], bfr[ni], acc[mi][ni], 0, 0, 0);
                    acc[mi][ni] = __builtin_amdgcn_mfma_f32_16x16x32_bf16(al[mi], bfr[ni], acc[mi][ni], 0, 0, 0);
                }
        }
        #pragma unroll
        for (int mi = 0; mi < 4; ++mi) {
            #pragma unroll
            for (int ni = 0; ni < 4; ++ni) {
                int col = ct * 128 + wc * 64 + ni * 16 + lr;
                float bv = wl1[((col & 127) << 3) + (col >> 7)];
                #pragma unroll
                for (int r = 0; r < 4; ++r) {
                    int row = row0 + wr * 64 + mi * 16 + lg * 4 + r;
                    if (row >= M) continue;
                    Y[(size_t)row * 1024 + col] = f2bf(acc[mi][ni][r] + bv);
                }
            }
        }
    }
}

// ========== rowdot8: out[r,s] = sum_d A[r,d]*W[d,s] (+bias8), W 128x8 ==========
template<int SPLITIN>
__global__ __launch_bounds__(256) void rowdot8(const short* __restrict__ Ah,
                                               const short* __restrict__ Al,
                                               const float* __restrict__ Wg,
                                               const float* __restrict__ bias8,
                                               float* __restrict__ out, int M) {
    __shared__ float sw[128][9];
    __shared__ float sb[8];
    for (int i = threadIdx.x; i < 1024; i += 256) sw[i >> 3][i & 7] = Wg[i];
    if (threadIdx.x < 8) sb[threadIdx.x] = bias8 ? bias8[threadIdx.x] : 0.f;
    __syncthreads();
    int r = blockIdx.x * 4 + (threadIdx.x >> 6);
    if (r >= M) return;
    int l = threadIdx.x & 63;
    int s = l & 7, c0 = (l >> 3) * 16;
    const short* ah = Ah + (size_t)r * 128 + c0;
    bf16x8 h0 = *reinterpret_cast<const bf16x8*>(ah);
    bf16x8 h1 = *reinterpret_cast<const bf16x8*>(ah + 8);
    float p = 0.f;
    if (SPLITIN) {
        const short* alr = Al + (size_t)r * 128 + c0;
        bf16x8 l0 = *reinterpret_cast<const bf16x8*>(alr);
        bf16x8 l1 = *reinterpret_cast<const bf16x8*>(alr + 8);
        #pragma unroll
        for (int j = 0; j < 8; ++j) {
            p += (bf2f(h0[j]) + bf2f(l0[j])) * sw[c0 + j][s];
            p += (bf2f(h1[j]) + bf2f(l1[j])) * sw[c0 + 8 + j][s];
        }
    } else {
        #pragma unroll
        for (int j = 0; j < 8; ++j) {
            p += bf2f(h0[j]) * sw[c0 + j][s];
            p += bf2f(h1[j]) * sw[c0 + 8 + j][s];
        }
    }
    p += __shfl_xor(p, 8); p += __shfl_xor(p, 16); p += __shfl_xor(p, 32);
    if (l < 8) out[(size_t)r * 8 + l] = p + sb[l];
}

// ========== fused edge kernel v2 (s-per-lane-group) ==========
__global__ __launch_bounds__(256) void edge_fused2(const short* __restrict__ xph,
                                                   const short* __restrict__ xpl,
                                                   const short* __restrict__ ep,
                                                   const short* __restrict__ Y,
                                                   const int* __restrict__ ei,
                                                   const float* __restrict__ u,
                                                   const float* __restrict__ v,
                                                   float* __restrict__ agg, int E) {
    int e = blockIdx.x * 4 + (threadIdx.x >> 6);
    if (e >= E) return;
    int l = threadIdx.x & 63;
    int s = l & 7, c0 = (l >> 3) * 16;
    int src = ei[e], dst = ei[E + e];
    const short* y  = Y + (size_t)src * 1024 + s * 128 + c0;
    const short* xih = xph + (size_t)dst * 128 + c0;
    const short* xil = xpl + (size_t)dst * 128 + c0;
    bf16x8 y0 = *reinterpret_cast<const bf16x8*>(y);
    bf16x8 y1 = *reinterpret_cast<const bf16x8*>(y + 8);
    bf16x8 a0 = *reinterpret_cast<const bf16x8*>(xih);
    bf16x8 a1 = *reinterpret_cast<const bf16x8*>(xih + 8);
    bf16x8 b0 = *reinterpret_cast<const bf16x8*>(xil);
    bf16x8 b1 = *reinterpret_cast<const bf16x8*>(xil + 8);
    float p = 0.f;
    #pragma unroll
    for (int j = 0; j < 8; ++j) {
        p += (bf2f(a0[j]) + bf2f(b0[j])) * bf2f(y0[j]);
        p += (bf2f(a1[j]) + bf2f(b1[j])) * bf2f(y1[j]);
    }
    p += __shfl_xor(p, 8); p += __shfl_xor(p, 16); p += __shfl_xor(p, 32);
    float alpha = tanhf(p + u[(size_t)src * 8 + s] + v[(size_t)e * 8 + s]);
    float aa0 = __shfl(alpha, l >> 4);
    float aa1 = __shfl(alpha, 4 + (l >> 4));
    float xj0 = bf2f(xph[(size_t)src * 128 + l]) + bf2f(xpl[(size_t)src * 128 + l]);
    float xj1 = bf2f(xph[(size_t)src * 128 + l + 64]) + bf2f(xpl[(size_t)src * 128 + l + 64]);
    float e0 = bf2f(ep[(size_t)e * 128 + l]);
    float e1 = bf2f(ep[(size_t)e * 128 + l + 64]);
    atomicAdd(&agg[(size_t)dst * 128 + l],      fmaxf(xj0, e0) * aa0);
    atomicAdd(&agg[(size_t)dst * 128 + l + 64], fmaxf(xj1, e1) * aa1);
}

// ========== gate GEMM (split-3, K=256 combined weights, in place) ==========
__global__ __launch_bounds__(256) void gate_gemm_split(float* __restrict__ h,
                                                       const float* __restrict__ aggv,
                                                       const short* __restrict__ BTh,  // [128][256]
                                                       const short* __restrict__ BTl,
                                                       const float* __restrict__ gb,
                                                       int M) {
    __shared__ short Ah[128][40];
    __shared__ short Al[128][40];
    __shared__ short Bh[128][40];
    __shared__ short Bl[128][40];
    const int tid = threadIdx.x;
    const int row0 = blockIdx.y * 128;
    const int lane = tid & 63, w = tid >> 6;
    const int wr = w >> 1, wc = w & 1;
    const int lr = lane & 15, lg = lane >> 4;
    f32x4 acc[4][4] = {};

    for (int k0 = 0; k0 < 256; k0 += 32) {
        int sec = k0 >> 7;
        #pragma unroll
        for (int i = 0; i < 4; ++i) {
            int idx = i * 256 + tid;
            int r = idx >> 3, q = idx & 7;
            int gr = row0 + r;
            int ks = (k0 & 127) + q * 4;
            f32x4 v;
            if (gr < M) {
                if (sec == 0) {
                    v = *reinterpret_cast<const f32x4*>(&h[(size_t)gr * 128 + ks]);
                } else {
                    f32x4 a = *reinterpret_cast<const f32x4*>(&aggv[(size_t)gr * 128 + ks]);
                    #pragma unroll
                    for (int j = 0; j < 4; ++j) v[j] = fmaxf(a[j], 0.f);
                }
            } else {
                #pragma unroll
                for (int j = 0; j < 4; ++j) v[j] = 0.f;
            }
            short4v hh, ll;
            #pragma unroll
            for (int j = 0; j < 4; ++j) {
                hh[j] = f2bf(v[j]);
                ll[j] = f2bf(v[j] - bf2f(hh[j]));
            }
            *reinterpret_cast<short4v*>(&Ah[r][q * 4]) = hh;
            *reinterpret_cast<short4v*>(&Al[r][q * 4]) = ll;
        }
        #pragma unroll
        for (int i = 0; i < 4; ++i) {
            int idx = i * 256 + tid;
            int r = idx >> 3, q = idx & 7;
            short4v uu = *reinterpret_cast<const short4v*>(&BTh[(size_t)r * 256 + k0 + q * 4]);
            short4v ul = *reinterpret_cast<const short4v*>(&BTl[(size_t)r * 256 + k0 + q * 4]);
            *reinterpret_cast<short4v*>(&Bh[r][q * 4]) = uu;
            *reinterpret_cast<short4v*>(&Bl[r][q * 4]) = ul;
        }
        __syncthreads();
        bf16x8 afh[4], afl[4], bfh[4], bfl[4];
        #pragma unroll
        for (int mi = 0; mi < 4; ++mi) {
            afh[mi] = *reinterpret_cast<const bf16x8*>(&Ah[wr * 64 + mi * 16 + lr][lg * 8]);
            afl[mi] = *reinterpret_cast<const bf16x8*>(&Al[wr * 64 + mi * 16 + lr][lg * 8]);
        }
        #pragma unroll
        for (int ni = 0; ni < 4; ++ni) {
            bfh[ni] = *reinterpret_cast<const bf16x8*>(&Bh[wc * 64 + ni * 16 + lr][lg * 8]);
            bfl[ni] = *reinterpret_cast<const bf16x8*>(&Bl[wc * 64 + ni * 16 + lr][lg * 8]);
        }
        #pragma unroll
        for (int mi = 0; mi < 4; ++mi)
            #pragma unroll
            for (int ni = 0; ni < 4; ++ni) {
                acc[mi][ni] = __builtin_amdgcn_mfma_f32_16x16x32_bf16(afh[mi], bfh[ni], acc[mi][ni], 0, 0, 0);
                acc[mi][ni] = __builtin_amdgcn_mfma_f32_16x16x32_bf16(afl[mi], bfh[ni], acc[mi][ni], 0, 0, 0);
                acc[mi][ni] = __builtin_amdgcn_mfma_f32_16x16x32_bf16(afh[mi], bfl[ni], acc[mi][ni], 0, 0, 0);
            }
        __syncthreads();
    }

    #pragma unroll
    for (int mi = 0; mi < 4; ++mi) {
        #pragma unroll
        for (int ni = 0; ni < 4; ++ni) {
            int col = wc * 64 + ni * 16 + lr;
            float gbv = gb[col];
            #pragma unroll
            for (int r = 0; r < 4; ++r) {
                int row = row0 + wr * 64 + mi * 16 + lg * 4 + r;
                if (row >= M) continue;
                float beta = fmaxf(acc[mi][ni][r] + gbv, 0.f);
                float hv = h[(size_t)row * 128 + col];
                float hh = fmaxf(aggv[(size_t)row * 128 + col], 0.f);
                h[(size_t)row * 128 + col] = beta * hv + (1.f - beta) * hh;
            }
        }
    }
}

// ========== batch norm (fp32 / bf16) ==========
__global__ void bn_stats(const float* __restrict__ z, float* __restrict__ gsum,
                         float* __restrict__ gsq, int M) {
    int c = threadIdx.x & 127;
    int rr = threadIdx.x >> 7;
    float s = 0.f, q = 0.f;
    for (int r = blockIdx.x * 2 + rr; r < M; r += gridDim.x * 2) {
        float v = z[(size_t)r * 128 + c];
        s += v; q += v * v;
    }
    __shared__ float ls[256], lq[256];
    ls[threadIdx.x] = s; lq[threadIdx.x] = q;
    __syncthreads();
    if (threadIdx.x < 128) {
        atomicAdd(&gsum[c], ls[threadIdx.x] + ls[threadIdx.x + 128]);
        atomicAdd(&gsq[c],  lq[threadIdx.x] + lq[threadIdx.x + 128]);
    }
}

__global__ void bn_apply(float* __restrict__ z, const float* __restrict__ gsum,
                         const float* __restrict__ gsq, const float* __restrict__ g,
                         const float* __restrict__ b, int M) {
    size_t total = (size_t)M * 128;
    for (size_t idx = (size_t)blockIdx.x * 256 + threadIdx.x; idx < total;
         idx += (size_t)gridDim.x * 256) {
        int c = idx & 127;
        float mu = gsum[c] / (float)M;
        float var = gsq[c] / (float)M - mu * mu;
        float rs = rsqrtf(var + EPS);
        float v = (z[idx] - mu) * rs * g[c] + b[c];
        z[idx] = fmaxf(v, 0.f);
    }
}

__global__ void bn_stats_bf(const short* __restrict__ z, float* __restrict__ gsum,
                            float* __restrict__ gsq, int M) {
    int c = threadIdx.x & 127;
    int rr = threadIdx.x >> 7;
    float s = 0.f, q = 0.f;
    for (int r = blockIdx.x * 2 + rr; r < M; r += gridDim.x * 2) {
        float v = bf2f(z[(size_t)r * 128 + c]);
        s += v; q += v * v;
    }
    __shared__ float ls[256], lq[256];
    ls[threadIdx.x] = s; lq[threadIdx.x] = q;
    __syncthreads();
    if (threadIdx.x < 128) {
        atomicAdd(&gsum[c], ls[threadIdx.x] + ls[threadIdx.x + 128]);
        atomicAdd(&gsq[c],  lq[threadIdx.x] + lq[threadIdx.x + 128]);
    }
}

__global__ void bn_apply_bf(short* __restrict__ z, const float* __restrict__ gsum,
                            const float* __restrict__ gsq, const float* __restrict__ g,
                            const float* __restrict__ b, int M) {
    size_t total = (size_t)M * 128;
    for (size_t idx = (size_t)blockIdx.x * 256 + threadIdx.x; idx < total;
         idx += (size_t)gridDim.x * 256) {
        int c = idx & 127;
        float mu = gsum[c] / (float)M;
        float var = gsq[c] / (float)M - mu * mu;
        float rs = rsqrtf(var + EPS);
        float v = (bf2f(z[idx]) - mu) * rs * g[c] + b[c];
        z[idx] = f2bf(fmaxf(v, 0.f));
    }
}

// ========== prep ==========
__global__ void transpose_split(const float* __restrict__ in, short* __restrict__ outh,
                                short* __restrict__ outl, int K, int N) {
    int idx = blockIdx.x * 256 + threadIdx.x;
    if (idx >= K * N) return;
    int nI = idx / K, k = idx - nI * K;
    float v = in[(size_t)k * N + nI];
    short h = f2bf(v);
    outh[idx] = h;
    outl[idx] = f2bf(v - bf2f(h));
}

__global__ void cvt_f2b(const float* __restrict__ in, short* __restrict__ out, int n) {
    int i = blockIdx.x * 256 + threadIdx.x;
    if (i < n) out[i] = f2bf(in[i]);
}

// combined gate weights: BT[n][k]: k<128 -> gw[k][n]+gw[256+k][n]; else gw[k][n]-gw[128+k... ]
__global__ void gate_combine_split(const float* __restrict__ gw, short* __restrict__ BTh,
                                   short* __restrict__ BTl) {
    int idx = blockIdx.x * 256 + threadIdx.x;
    if (idx >= 128 * 256) return;
    int n = idx >> 8, k = idx & 255;
    float v;
    if (k < 128) v = gw[(size_t)k * 128 + n] + gw[(size_t)(256 + k) * 128 + n];
    else {
        int kk = k - 128;
        v = gw[(size_t)(128 + kk) * 128 + n] - gw[(size_t)(256 + kk) * 128 + n];
    }
    short h = f2bf(v);
    BTh[idx] = h;
    BTl[idx] = f2bf(v - bf2f(h));
}

__global__ void build_wm(const float* __restrict__ wsrc, float* __restrict__ wm) {
    int idx = blockIdx.x * 256 + threadIdx.x;
    if (idx >= 128 * 128) return;
    int d = idx >> 7, c = idx & 127;
    float s = 0.f;
    #pragma unroll
    for (int h = 0; h < 8; ++h) s += wsrc[(size_t)d * 1024 + h * 128 + c];
    wm[idx] = s * 0.125f;
}

__global__ void perm_build(const int* __restrict__ ci, int* __restrict__ perm, int NF) {
    int i = blockIdx.x * 256 + threadIdx.x;
    if (i >= NF) return;
    int c = ci[i];
    if (i == 0 || ci[i - 1] != c) perm[c] = i;
}

__global__ void seg_pool(const float* __restrict__ fx, const int* __restrict__ perm,
                         float* __restrict__ pool, int F, int NF) {
    int idx = blockIdx.x * 256 + threadIdx.x;
    if (idx >= F * 128) return;
    int f = idx >> 7, c = idx & 127;
    int s = perm[f];
    int e = (f + 1 < F) ? perm[f + 1] : NF;
    float acc = 0.f;
    for (int i = s; i < e; ++i) acc += fx[(size_t)i * 128 + c];
    pool[idx] = fmaxf(acc, 0.f);
}

// ========== output ==========
__global__ __launch_bounds__(256) void out_phase1(const float* __restrict__ h,
                                                  const float* __restrict__ out_w,
                                                  const float* __restrict__ out_b,
                                                  const float* __restrict__ gat_bias,
                                                  float* __restrict__ out, int M) {
    int n = blockIdx.x * 4 + (threadIdx.x >> 6);
    if (n >= M) return;
    int l = threadIdx.x & 63;
    float p = fmaxf(h[(size_t)n * 128 + l], 0.f) * out_w[l]
            + fmaxf(h[(size_t)n * 128 + l + 64], 0.f) * out_w[l + 64];
    p += fmaxf(gat_bias[l], 0.f) * out_w[128 + l]
       + fmaxf(gat_bias[l + 64], 0.f) * out_w[128 + l + 64];
    #pragma unroll
    for (int off = 32; off; off >>= 1) p += __shfl_xor(p, off);
    if (l == 0) out[n] = p + out_b[0];
}

__global__ __launch_bounds__(256) void out_phase2(const float* __restrict__ fmv,
                                                  const int* __restrict__ perm,
                                                  const float* __restrict__ out_w,
                                                  const float* __restrict__ gat_bias,
                                                  float* __restrict__ out, int F) {
    int f = blockIdx.x * 4 + (threadIdx.x >> 6);
    if (f >= F) return;
    int l = threadIdx.x & 63;
    float p = fmv[(size_t)f * 128 + l] * out_w[128 + l]
            + fmv[(size_t)f * 128 + l + 64] * out_w[128 + l + 64];
    float b = fmaxf(gat_bias[l], 0.f) * out_w[128 + l]
            + fmaxf(gat_bias[l + 64], 0.f) * out_w[128 + l + 64];
    float d = p - b;
    #pragma unroll
    for (int off = 32; off; off >>= 1) d += __shfl_xor(d, off);
    if (l == 0) out[perm[f]] += d;
}

// ========== host ==========
extern "C" void kernel_launch(void* const* d_in, const int* in_sizes, int n_in,
                              void* d_out, int out_size, void* d_ws, size_t ws_size,
                              hipStream_t stream) {
    const int N = 50000, E = 100000, NF = 20000, EF = 40000, F = 10000;

    const float* x          = (const float*)d_in[0];
    const float* edge_attr  = (const float*)d_in[1];
    const float* frag_x     = (const float*)d_in[2];
    const float* frag_ea    = (const float*)d_in[3];
    const float* la_w = (const float*)d_in[4];
    const float* la_b = (const float*)d_in[5];
    const float* lb_w = (const float*)d_in[6];
    const float* lb_b = (const float*)d_in[7];
    const float* bn1_g = (const float*)d_in[8];
    const float* bn1_b = (const float*)d_in[9];
    const float* bn2_g = (const float*)d_in[10];
    const float* bn2_b = (const float*)d_in[11];
    const float* wn = (const float*)d_in[12];
    const float* wb = (const float*)d_in[13];
    const float* wl = (const float*)d_in[14];
    const float* wlb = (const float*)d_in[15];
    const float* gate_w = (const float*)d_in[16];
    const float* gate_b = (const float*)d_in[17];
    const float* gat_wsrc = (const float*)d_in[18];
    const float* gat_bias = (const float*)d_in[22];
    const float* out_w = (const float*)d_in[23];
    const float* out_b = (const float*)d_in[24];
    const int* edge_index = (const int*)d_in[25];
    const int* frag_edge_index = (const int*)d_in[26];
    const int* cluster_index = (const int*)d_in[27];

    char* p = (char*)d_ws;
    auto alloc = [&](size_t bytes) { char* r = p; p += (bytes + 255) & ~(size_t)255; return (void*)r; };
    float* hA    = (float*)alloc((size_t)N * 128 * 4);
    short* ea1   = (short*)alloc((size_t)E * 128 * 2);
    short* xph   = (short*)alloc((size_t)N * 128 * 2);
    short* xpl   = (short*)alloc((size_t)N * 128 * 2);
    short* ep    = (short*)alloc((size_t)E * 128 * 2);
    short* Y     = (short*)alloc((size_t)N * 1024 * 2);
    float* agg   = (float*)alloc((size_t)N * 128 * 4);
    float* ubuf  = (float*)alloc((size_t)N * 8 * 4);
    float* vbuf  = (float*)alloc((size_t)E * 8 * 4);
    short* la_wTh = (short*)alloc(128 * 128 * 2);
    short* la_wTl = (short*)alloc(128 * 128 * 2);
    short* lb_wTh = (short*)alloc(128 * 16 * 2);
    short* lb_wTl = (short*)alloc(128 * 16 * 2);
    short* wnTh   = (short*)alloc(3 * 128 * 128 * 2);
    short* wnTl   = (short*)alloc(3 * 128 * 128 * 2);
    short* wbH    = (short*)alloc(3 * 1024 * 128 * 2);
    short* gate2Th = (short*)alloc(128 * 256 * 2);
    short* gate2Tl = (short*)alloc(128 * 256 * 2);
    float* wmF    = (float*)alloc(128 * 128 * 4);
    short* wmTh   = (short*)alloc(128 * 128 * 2);
    short* wmTl   = (short*)alloc(128 * 128 * 2);
    float* stats  = (float*)alloc(256 * 4);
    char* yq = (char*)Y;
    float* fpool = (float*)yq;              yq += (size_t)F * 128 * 4;
    float* fmv   = (float*)yq;              yq += (size_t)F * 128 * 4;
    int*   perm  = (int*)yq;

    auto cdiv = [](int a, int b) { return (a + b - 1) / b; };

    // ---- weight prep ----
    transpose_split<<<cdiv(128 * 128, 256), 256, 0, stream>>>(la_w, la_wTh, la_wTl, 128, 128);
    transpose_split<<<cdiv(16 * 128, 256), 256, 0, stream>>>(lb_w, lb_wTh, lb_wTl, 16, 128);
    for (int l = 0; l < 3; ++l)
        transpose_split<<<cdiv(128 * 128, 256), 256, 0, stream>>>(
            wn + (size_t)l * 16384, wnTh + (size_t)l * 16384, wnTl + (size_t)l * 16384, 128, 128);
    cvt_f2b<<<cdiv(3 * 1024 * 128, 256), 256, 0, stream>>>(wb, wbH, 3 * 1024 * 128);
    gate_combine_split<<<cdiv(128 * 256, 256), 256, 0, stream>>>(gate_w, gate2Th, gate2Tl);
    build_wm<<<cdiv(128 * 128, 256), 256, 0, stream>>>(gat_wsrc, wmF);
    transpose_split<<<cdiv(128 * 128, 256), 256, 0, stream>>>(wmF, wmTh, wmTl, 128, 128);

    auto run_layer = [&](float* h, const short* ea_buf, const int* ei, int Mn, int Me, int layer) {
        const short* wnTh_l = wnTh + (size_t)layer * 16384;
        const short* wnTl_l = wnTl + (size_t)layer * 16384;
        const short* wb_l   = wbH + (size_t)layer * 131072;
        const float* wl_l   = wl + (size_t)layer * 384 * 8;
        const float* wlb_l  = wlb + (size_t)layer * 8;
        gemm_split<3, 0, 2><<<dim3(1, cdiv(Mn, 128)), 256, 0, stream>>>(h, wnTh_l, wnTl_l, nullptr, xph, xpl, Mn, 128, 128);
        gemm_bf16<0, 1><<<dim3(1, cdiv(Me, 128)), 256, 0, stream>>>(ea_buf, wnTh_l, nullptr, ep, Me, 128, 128);
        gemm_y<<<cdiv(Mn, 128), 256, 0, stream>>>(xph, xpl, wb_l, wl_l, Y, Mn);
        rowdot8<1><<<cdiv(Mn, 4), 256, 0, stream>>>(xph, xpl, wl_l + 256 * 8, wlb_l, ubuf, Mn);
        rowdot8<0><<<cdiv(Me, 4), 256, 0, stream>>>(ep, nullptr, wl_l + 128 * 8, nullptr, vbuf, Me);
        hipMemsetAsync(agg, 0, (size_t)Mn * 128 * 4, stream);
        edge_fused2<<<cdiv(Me, 4), 256, 0, stream>>>(xph, xpl, ep, Y, ei, ubuf, vbuf, agg, Me);
        gate_gemm_split<<<dim3(1, cdiv(Mn, 128)), 256, 0, stream>>>(h, agg, gate2Th, gate2Tl, gate_b, Mn);
    };

    // ---- atom path ----
    gemm_split<3, 0, 0><<<dim3(1, cdiv(N, 128)), 256, 0, stream>>>(x, la_wTh, la_wTl, la_b, hA, nullptr, N, 128, 128);
    hipMemsetAsync(stats, 0, 1024, stream);
    bn_stats<<<256, 256, 0, stream>>>(hA, stats, stats + 128, N);
    bn_apply<<<2048, 256, 0, stream>>>(hA, stats, stats + 128, bn1_g, bn1_b, N);

    gemm_split<3, 0, 1><<<dim3(1, cdiv(E, 128)), 256, 0, stream>>>(edge_attr, lb_wTh, lb_wTl, lb_b, ea1, nullptr, E, 128, 16);
    hipMemsetAsync(stats, 0, 1024, stream);
    bn_stats_bf<<<256, 256, 0, stream>>>(ea1, stats, stats + 128, E);
    bn_apply_bf<<<2048, 256, 0, stream>>>(ea1, stats, stats + 128, bn2_g, bn2_b, E);

    for (int l = 0; l < 3; ++l) run_layer(hA, ea1, edge_index, N, E, l);
    out_phase1<<<cdiv(N, 4), 256, 0, stream>>>(hA, out_w, out_b, gat_bias, (float*)d_out, N);

    // ---- fragment path ----
    gemm_split<3, 1, 0><<<dim3(1, cdiv(NF, 128)), 256, 0, stream>>>(frag_x, la_wTh, la_wTl, la_b, hA, nullptr, NF, 128, 128);

    gemm_split<3, 0, 1><<<dim3(1, cdiv(EF, 128)), 256, 0, stream>>>(frag_ea, lb_wTh, lb_wTl, lb_b, ea1, nullptr, EF, 128, 16);
    hipMemsetAsync(stats, 0, 1024, stream);
    bn_stats_bf<<<256, 256, 0, stream>>>(ea1, stats, stats + 128, EF);
    bn_apply_bf<<<2048, 256, 0, stream>>>(ea1, stats, stats + 128, bn2_g, bn2_b, EF);

    for (int l = 0; l < 3; ++l) run_layer(hA, ea1, frag_edge_index, NF, EF, l);

    perm_build<<<cdiv(NF, 256), 256, 0, stream>>>(cluster_index, perm, NF);
    seg_pool<<<cdiv(F * 128, 256), 256, 0, stream>>>(hA, perm, fpool, F, NF);
    gemm_split<3, 1, 0><<<dim3(1, cdiv(F, 128)), 256, 0, stream>>>(fpool, wmTh, wmTl, gat_bias, fmv, nullptr, F, 128, 128);
    out_phase2<<<cdiv(F, 4), 256, 0, stream>>>(fmv, perm, out_w, gat_bias, (float*)d_out, F);
}

// Round 7
// 1616.956 us; speedup vs baseline: 1.1582x; 1.1582x over previous
//
#include <hip/hip_runtime.h>
#include <hip/hip_bf16.h>

#define EPS 1e-5f

typedef short bf16x8 __attribute__((ext_vector_type(8)));
typedef short short4v __attribute__((ext_vector_type(4)));
typedef float f32x4 __attribute__((ext_vector_type(4)));

static __device__ __forceinline__ short f2bf(float x) {
    __hip_bfloat16 h = __float2bfloat16(x);
    return *reinterpret_cast<short*>(&h);
}
static __device__ __forceinline__ float bf2f(short x) {
    __hip_bfloat16 h;
    *reinterpret_cast<short*>(&h) = x;
    return __bfloat162float(h);
}

// ========== split-bf16 MFMA GEMM: C = act(A[M,K](f32) @ BT[N,K]^T + bias) ==========
template<int SPLIT, int ACT, int OUTM>
__global__ __launch_bounds__(256) void gemm_split(const float* __restrict__ A,
                                                  const short* __restrict__ BTh,
                                                  const short* __restrict__ BTl,
                                                  const float* __restrict__ bias,
                                                  void* __restrict__ Cout,
                                                  void* __restrict__ Cout2,
                                                  int M, int N, int K) {
    __shared__ short Ah[128][40];
    __shared__ short Al[128][40];
    __shared__ short Bh[128][40];
    __shared__ short Bl[128][40];
    const int tid = threadIdx.x;
    const int row0 = blockIdx.y * 128, col0 = blockIdx.x * 128;
    const int lane = tid & 63, w = tid >> 6;
    const int wr = w >> 1, wc = w & 1;
    const int lr = lane & 15, lg = lane >> 4;
    f32x4 acc[4][4] = {};

    for (int k0 = 0; k0 < K; k0 += 32) {
        #pragma unroll
        for (int i = 0; i < 4; ++i) {
            int idx = i * 256 + tid;
            int r = idx >> 3, q = idx & 7;
            int gr = row0 + r, gk = k0 + q * 4;
            f32x4 v;
            if (gr < M && gk + 3 < K) {
                v = *reinterpret_cast<const f32x4*>(&A[(size_t)gr * K + gk]);
            } else {
                #pragma unroll
                for (int j = 0; j < 4; ++j)
                    v[j] = (gr < M && gk + j < K) ? A[(size_t)gr * K + gk + j] : 0.f;
            }
            short4v h, l;
            #pragma unroll
            for (int j = 0; j < 4; ++j) {
                h[j] = f2bf(v[j]);
                l[j] = f2bf(v[j] - bf2f(h[j]));
            }
            *reinterpret_cast<short4v*>(&Ah[r][q * 4]) = h;
            *reinterpret_cast<short4v*>(&Al[r][q * 4]) = l;
        }
        #pragma unroll
        for (int i = 0; i < 4; ++i) {
            int idx = i * 256 + tid;
            int r = idx >> 3, q = idx & 7;
            int gc = col0 + r, gk = k0 + q * 4;
            short4v u, ul;
            if (gk + 3 < K) {
                u = *reinterpret_cast<const short4v*>(&BTh[(size_t)gc * K + gk]);
                if (SPLIT == 3) ul = *reinterpret_cast<const short4v*>(&BTl[(size_t)gc * K + gk]);
            } else {
                #pragma unroll
                for (int j = 0; j < 4; ++j) {
                    u[j] = (gk + j < K) ? BTh[(size_t)gc * K + gk + j] : (short)0;
                    if (SPLIT == 3) ul[j] = (gk + j < K) ? BTl[(size_t)gc * K + gk + j] : (short)0;
                }
            }
            *reinterpret_cast<short4v*>(&Bh[r][q * 4]) = u;
            if (SPLIT == 3) *reinterpret_cast<short4v*>(&Bl[r][q * 4]) = ul;
        }
        __syncthreads();
        bf16x8 afh[4], afl[4], bfh[4];
        #pragma unroll
        for (int mi = 0; mi < 4; ++mi) {
            afh[mi] = *reinterpret_cast<const bf16x8*>(&Ah[wr * 64 + mi * 16 + lr][lg * 8]);
            afl[mi] = *reinterpret_cast<const bf16x8*>(&Al[wr * 64 + mi * 16 + lr][lg * 8]);
        }
        #pragma unroll
        for (int ni = 0; ni < 4; ++ni)
            bfh[ni] = *reinterpret_cast<const bf16x8*>(&Bh[wc * 64 + ni * 16 + lr][lg * 8]);
        #pragma unroll
        for (int mi = 0; mi < 4; ++mi)
            #pragma unroll
            for (int ni = 0; ni < 4; ++ni) {
                acc[mi][ni] = __builtin_amdgcn_mfma_f32_16x16x32_bf16(afh[mi], bfh[ni], acc[mi][ni], 0, 0, 0);
                acc[mi][ni] = __builtin_amdgcn_mfma_f32_16x16x32_bf16(afl[mi], bfh[ni], acc[mi][ni], 0, 0, 0);
            }
        if (SPLIT == 3) {
            bf16x8 bfl[4];
            #pragma unroll
            for (int ni = 0; ni < 4; ++ni)
                bfl[ni] = *reinterpret_cast<const bf16x8*>(&Bl[wc * 64 + ni * 16 + lr][lg * 8]);
            #pragma unroll
            for (int mi = 0; mi < 4; ++mi)
                #pragma unroll
                for (int ni = 0; ni < 4; ++ni)
                    acc[mi][ni] = __builtin_amdgcn_mfma_f32_16x16x32_bf16(afh[mi], bfl[ni], acc[mi][ni], 0, 0, 0);
        }
        __syncthreads();
    }

    #pragma unroll
    for (int mi = 0; mi < 4; ++mi) {
        #pragma unroll
        for (int ni = 0; ni < 4; ++ni) {
            int col = col0 + wc * 64 + ni * 16 + lr;
            float bv = bias ? bias[col] : 0.f;
            #pragma unroll
            for (int r = 0; r < 4; ++r) {
                int row = row0 + wr * 64 + mi * 16 + lg * 4 + r;
                if (row >= M) continue;
                float v = acc[mi][ni][r] + bv;
                if (ACT) v = fmaxf(v, 0.f);
                if (OUTM == 0) ((float*)Cout)[(size_t)row * N + col] = v;
                else ((short*)Cout)[(size_t)row * N + col] = f2bf(v);
            }
        }
    }
}

// ========== plain bf16 GEMM (tolerant path: ep projection) ==========
template<int ACT, int OUTBF>
__global__ __launch_bounds__(256) void gemm_bf16(const short* __restrict__ A,
                                                 const short* __restrict__ BT,
                                                 const float* __restrict__ bias,
                                                 void* __restrict__ Cout,
                                                 int M, int N, int K) {
    __shared__ short As[128][40];
    __shared__ short Bs[128][40];
    const int tid = threadIdx.x;
    const int row0 = blockIdx.y * 128, col0 = blockIdx.x * 128;
    const int lane = tid & 63, w = tid >> 6;
    const int wr = w >> 1, wc = w & 1;
    const int lr = lane & 15, lg = lane >> 4;
    f32x4 acc[4][4] = {};

    for (int k0 = 0; k0 < K; k0 += 32) {
        #pragma unroll
        for (int i = 0; i < 4; ++i) {
            int idx = i * 256 + tid;
            int r = idx >> 3, q = idx & 7;
            int gk = k0 + q * 4;
            int gr = row0 + r;
            short4v v;
            if (gr < M && gk + 3 < K) {
                v = *reinterpret_cast<const short4v*>(&A[(size_t)gr * K + gk]);
            } else {
                #pragma unroll
                for (int j = 0; j < 4; ++j)
                    v[j] = (gr < M && gk + j < K) ? A[(size_t)gr * K + gk + j] : (short)0;
            }
            *reinterpret_cast<short4v*>(&As[r][q * 4]) = v;
            int gc = col0 + r;
            short4v u;
            if (gc < N && gk + 3 < K) {
                u = *reinterpret_cast<const short4v*>(&BT[(size_t)gc * K + gk]);
            } else {
                #pragma unroll
                for (int j = 0; j < 4; ++j)
                    u[j] = (gc < N && gk + j < K) ? BT[(size_t)gc * K + gk + j] : (short)0;
            }
            *reinterpret_cast<short4v*>(&Bs[r][q * 4]) = u;
        }
        __syncthreads();
        bf16x8 af[4], bfr[4];
        #pragma unroll
        for (int mi = 0; mi < 4; ++mi)
            af[mi] = *reinterpret_cast<const bf16x8*>(&As[wr * 64 + mi * 16 + lr][lg * 8]);
        #pragma unroll
        for (int ni = 0; ni < 4; ++ni)
            bfr[ni] = *reinterpret_cast<const bf16x8*>(&Bs[wc * 64 + ni * 16 + lr][lg * 8]);
        #pragma unroll
        for (int mi = 0; mi < 4; ++mi)
            #pragma unroll
            for (int ni = 0; ni < 4; ++ni)
                acc[mi][ni] = __builtin_amdgcn_mfma_f32_16x16x32_bf16(af[mi], bfr[ni], acc[mi][ni], 0, 0, 0);
        __syncthreads();
    }

    #pragma unroll
    for (int mi = 0; mi < 4; ++mi) {
        #pragma unroll
        for (int ni = 0; ni < 4; ++ni) {
            int col = col0 + wc * 64 + ni * 16 + lr;
            float bv = bias ? bias[col] : 0.f;
            #pragma unroll
            for (int r = 0; r < 4; ++r) {
                int row = row0 + wr * 64 + mi * 16 + lg * 4 + r;
                if (row >= M) continue;
                float v = acc[mi][ni][r] + bv;
                if (ACT) v = fmaxf(v, 0.f);
                if (OUTBF) ((short*)Cout)[(size_t)row * N + col] = f2bf(v);
                else       ((float*)Cout)[(size_t)row * N + col] = v;
            }
        }
    }
}

// ========== fused xp + Y kernel ==========
// Phase 1: xp[128rows,128] = h @ wnT (split-3), written hi/lo to LDS + global.
// Phase 2: Y[128rows,1024] = (xp_hi+xp_lo) @ wbBT^T + wl1 colbias, B from global (L2).
// 512 threads = 8 waves (2 row-halves x 4 col-quarters).
__global__ __launch_bounds__(512) void fused_xpy(const float* __restrict__ h,
                                                 const short* __restrict__ wnTh,
                                                 const short* __restrict__ wnTl,
                                                 const short* __restrict__ wbBT,
                                                 const float* __restrict__ wl1,
                                                 short* __restrict__ xph,
                                                 short* __restrict__ xpl,
                                                 short* __restrict__ Y, int M) {
    __shared__ short xpH[128 * 136];
    __shared__ short xpL[128 * 136];
    // phase-1 staging aliases (each 128x40 shorts = 5120)
    short* Ah = xpH;
    short* Bh = xpH + 5120;
    short* Al = xpL;
    short* Bl = xpL + 5120;

    const int tid = threadIdx.x;
    const int row0 = blockIdx.x * 128;
    const int lane = tid & 63, w = tid >> 6;
    const int wr = w >> 2, wc = w & 3;          // 2 x 4 wave grid
    const int lr = lane & 15, lg = lane >> 4;

    // ---- phase 1: xp = h @ wnT, split-3 ----
    f32x4 acc1[4][2] = {};
    for (int k0 = 0; k0 < 128; k0 += 32) {
        #pragma unroll
        for (int i = 0; i < 2; ++i) {
            int idx = i * 512 + tid;           // 1024 = 128 rows x 8 chunks
            int r = idx >> 3, q = idx & 7;
            int gr = row0 + r, gk = k0 + q * 4;
            f32x4 v;
            if (gr < M) {
                v = *reinterpret_cast<const f32x4*>(&h[(size_t)gr * 128 + gk]);
            } else {
                #pragma unroll
                for (int j = 0; j < 4; ++j) v[j] = 0.f;
            }
            short4v hh, ll;
            #pragma unroll
            for (int j = 0; j < 4; ++j) {
                hh[j] = f2bf(v[j]);
                ll[j] = f2bf(v[j] - bf2f(hh[j]));
            }
            *reinterpret_cast<short4v*>(&Ah[r * 40 + q * 4]) = hh;
            *reinterpret_cast<short4v*>(&Al[r * 40 + q * 4]) = ll;
            // B tile (wnT [128][128])
            short4v bh = *reinterpret_cast<const short4v*>(&wnTh[(size_t)r * 128 + gk]);
            short4v bl = *reinterpret_cast<const short4v*>(&wnTl[(size_t)r * 128 + gk]);
            *reinterpret_cast<short4v*>(&Bh[r * 40 + q * 4]) = bh;
            *reinterpret_cast<short4v*>(&Bl[r * 40 + q * 4]) = bl;
        }
        __syncthreads();
        bf16x8 afh[4], afl[4], bfh[2], bfl[2];
        #pragma unroll
        for (int mi = 0; mi < 4; ++mi) {
            afh[mi] = *reinterpret_cast<const bf16x8*>(&Ah[(wr * 64 + mi * 16 + lr) * 40 + lg * 8]);
            afl[mi] = *reinterpret_cast<const bf16x8*>(&Al[(wr * 64 + mi * 16 + lr) * 40 + lg * 8]);
        }
        #pragma unroll
        for (int ni = 0; ni < 2; ++ni) {
            bfh[ni] = *reinterpret_cast<const bf16x8*>(&Bh[(wc * 32 + ni * 16 + lr) * 40 + lg * 8]);
            bfl[ni] = *reinterpret_cast<const bf16x8*>(&Bl[(wc * 32 + ni * 16 + lr) * 40 + lg * 8]);
        }
        #pragma unroll
        for (int mi = 0; mi < 4; ++mi)
            #pragma unroll
            for (int ni = 0; ni < 2; ++ni) {
                acc1[mi][ni] = __builtin_amdgcn_mfma_f32_16x16x32_bf16(afh[mi], bfh[ni], acc1[mi][ni], 0, 0, 0);
                acc1[mi][ni] = __builtin_amdgcn_mfma_f32_16x16x32_bf16(afl[mi], bfh[ni], acc1[mi][ni], 0, 0, 0);
                acc1[mi][ni] = __builtin_amdgcn_mfma_f32_16x16x32_bf16(afh[mi], bfl[ni], acc1[mi][ni], 0, 0, 0);
            }
        __syncthreads();
    }

    // ---- write xp (hi/lo) to LDS + global ----
    #pragma unroll
    for (int mi = 0; mi < 4; ++mi) {
        #pragma unroll
        for (int ni = 0; ni < 2; ++ni) {
            int col = wc * 32 + ni * 16 + lr;
            #pragma unroll
            for (int r = 0; r < 4; ++r) {
                int rl = wr * 64 + mi * 16 + lg * 4 + r;
                float v = acc1[mi][ni][r];
                short hi = f2bf(v);
                short lo = f2bf(v - bf2f(hi));
                xpH[rl * 136 + col] = hi;
                xpL[rl * 136 + col] = lo;
                int row = row0 + rl;
                if (row < M) {
                    xph[(size_t)row * 128 + col] = hi;
                    xpl[(size_t)row * 128 + col] = lo;
                }
            }
        }
    }
    __syncthreads();

    // ---- phase 2: Y = (xpH+xpL) @ wbBT^T + colbias ----
    for (int ct = 0; ct < 8; ++ct) {
        f32x4 acc[4][2] = {};
        #pragma unroll
        for (int k = 0; k < 4; ++k) {
            bf16x8 bfr[2];
            #pragma unroll
            for (int ni = 0; ni < 2; ++ni) {
                int col = ct * 128 + wc * 32 + ni * 16 + lr;
                bfr[ni] = *reinterpret_cast<const bf16x8*>(&wbBT[(size_t)col * 128 + k * 32 + lg * 8]);
            }
            bf16x8 ah[4], al[4];
            #pragma unroll
            for (int mi = 0; mi < 4; ++mi) {
                ah[mi] = *reinterpret_cast<const bf16x8*>(&xpH[(wr * 64 + mi * 16 + lr) * 136 + k * 32 + lg * 8]);
                al[mi] = *reinterpret_cast<const bf16x8*>(&xpL[(wr * 64 + mi * 16 + lr) * 136 + k * 32 + lg * 8]);
            }
            #pragma unroll
            for (int mi = 0; mi < 4; ++mi)
                #pragma unroll
                for (int ni = 0; ni < 2; ++ni) {
                    acc[mi][ni] = __builtin_amdgcn_mfma_f32_16x16x32_bf16(ah[mi], bfr[ni], acc[mi][ni], 0, 0, 0);
                    acc[mi][ni] = __builtin_amdgcn_mfma_f32_16x16x32_bf16(al[mi], bfr[ni], acc[mi][ni], 0, 0, 0);
                }
        }
        #pragma unroll
        for (int mi = 0; mi < 4; ++mi) {
            #pragma unroll
            for (int ni = 0; ni < 2; ++ni) {
                int col = ct * 128 + wc * 32 + ni * 16 + lr;
                float bv = wl1[((col & 127) << 3) + (col >> 7)];
                #pragma unroll
                for (int r = 0; r < 4; ++r) {
                    int row = row0 + wr * 64 + mi * 16 + lg * 4 + r;
                    if (row >= M) continue;
                    Y[(size_t)row * 1024 + col] = f2bf(acc[mi][ni][r] + bv);
                }
            }
        }
    }
}

// ========== rowdot8 ==========
template<int SPLITIN>
__global__ __launch_bounds__(256) void rowdot8(const short* __restrict__ Ah,
                                               const short* __restrict__ Al,
                                               const float* __restrict__ Wg,
                                               const float* __restrict__ bias8,
                                               float* __restrict__ out, int M) {
    __shared__ float sw[128][9];
    __shared__ float sb[8];
    for (int i = threadIdx.x; i < 1024; i += 256) sw[i >> 3][i & 7] = Wg[i];
    if (threadIdx.x < 8) sb[threadIdx.x] = bias8 ? bias8[threadIdx.x] : 0.f;
    __syncthreads();
    int r = blockIdx.x * 4 + (threadIdx.x >> 6);
    if (r >= M) return;
    int l = threadIdx.x & 63;
    int s = l & 7, c0 = (l >> 3) * 16;
    const short* ah = Ah + (size_t)r * 128 + c0;
    bf16x8 h0 = *reinterpret_cast<const bf16x8*>(ah);
    bf16x8 h1 = *reinterpret_cast<const bf16x8*>(ah + 8);
    float p = 0.f;
    if (SPLITIN) {
        const short* alr = Al + (size_t)r * 128 + c0;
        bf16x8 l0 = *reinterpret_cast<const bf16x8*>(alr);
        bf16x8 l1 = *reinterpret_cast<const bf16x8*>(alr + 8);
        #pragma unroll
        for (int j = 0; j < 8; ++j) {
            p += (bf2f(h0[j]) + bf2f(l0[j])) * sw[c0 + j][s];
            p += (bf2f(h1[j]) + bf2f(l1[j])) * sw[c0 + 8 + j][s];
        }
    } else {
        #pragma unroll
        for (int j = 0; j < 8; ++j) {
            p += bf2f(h0[j]) * sw[c0 + j][s];
            p += bf2f(h1[j]) * sw[c0 + 8 + j][s];
        }
    }
    p += __shfl_xor(p, 8); p += __shfl_xor(p, 16); p += __shfl_xor(p, 32);
    if (l < 8) out[(size_t)r * 8 + l] = p + sb[l];
}

// ========== fused edge kernel v2 ==========
__global__ __launch_bounds__(256) void edge_fused2(const short* __restrict__ xph,
                                                   const short* __restrict__ xpl,
                                                   const short* __restrict__ ep,
                                                   const short* __restrict__ Y,
                                                   const int* __restrict__ ei,
                                                   const float* __restrict__ u,
                                                   const float* __restrict__ v,
                                                   float* __restrict__ agg, int E) {
    int e = blockIdx.x * 4 + (threadIdx.x >> 6);
    if (e >= E) return;
    int l = threadIdx.x & 63;
    int s = l & 7, c0 = (l >> 3) * 16;
    int src = ei[e], dst = ei[E + e];
    const short* y  = Y + (size_t)src * 1024 + s * 128 + c0;
    const short* xih = xph + (size_t)dst * 128 + c0;
    const short* xil = xpl + (size_t)dst * 128 + c0;
    bf16x8 y0 = *reinterpret_cast<const bf16x8*>(y);
    bf16x8 y1 = *reinterpret_cast<const bf16x8*>(y + 8);
    bf16x8 a0 = *reinterpret_cast<const bf16x8*>(xih);
    bf16x8 a1 = *reinterpret_cast<const bf16x8*>(xih + 8);
    bf16x8 b0 = *reinterpret_cast<const bf16x8*>(xil);
    bf16x8 b1 = *reinterpret_cast<const bf16x8*>(xil + 8);
    float p = 0.f;
    #pragma unroll
    for (int j = 0; j < 8; ++j) {
        p += (bf2f(a0[j]) + bf2f(b0[j])) * bf2f(y0[j]);
        p += (bf2f(a1[j]) + bf2f(b1[j])) * bf2f(y1[j]);
    }
    p += __shfl_xor(p, 8); p += __shfl_xor(p, 16); p += __shfl_xor(p, 32);
    float alpha = tanhf(p + u[(size_t)src * 8 + s] + v[(size_t)e * 8 + s]);
    float aa0 = __shfl(alpha, l >> 4);
    float aa1 = __shfl(alpha, 4 + (l >> 4));
    float xj0 = bf2f(xph[(size_t)src * 128 + l]) + bf2f(xpl[(size_t)src * 128 + l]);
    float xj1 = bf2f(xph[(size_t)src * 128 + l + 64]) + bf2f(xpl[(size_t)src * 128 + l + 64]);
    float e0 = bf2f(ep[(size_t)e * 128 + l]);
    float e1 = bf2f(ep[(size_t)e * 128 + l + 64]);
    atomicAdd(&agg[(size_t)dst * 128 + l],      fmaxf(xj0, e0) * aa0);
    atomicAdd(&agg[(size_t)dst * 128 + l + 64], fmaxf(xj1, e1) * aa1);
}

// ========== gate GEMM (split-3, K=256 combined weights, in place) ==========
__global__ __launch_bounds__(256) void gate_gemm_split(float* __restrict__ h,
                                                       const float* __restrict__ aggv,
                                                       const short* __restrict__ BTh,
                                                       const short* __restrict__ BTl,
                                                       const float* __restrict__ gb,
                                                       int M) {
    __shared__ short Ah[128][40];
    __shared__ short Al[128][40];
    __shared__ short Bh[128][40];
    __shared__ short Bl[128][40];
    const int tid = threadIdx.x;
    const int row0 = blockIdx.y * 128;
    const int lane = tid & 63, w = tid >> 6;
    const int wr = w >> 1, wc = w & 1;
    const int lr = lane & 15, lg = lane >> 4;
    f32x4 acc[4][4] = {};

    for (int k0 = 0; k0 < 256; k0 += 32) {
        int sec = k0 >> 7;
        #pragma unroll
        for (int i = 0; i < 4; ++i) {
            int idx = i * 256 + tid;
            int r = idx >> 3, q = idx & 7;
            int gr = row0 + r;
            int ks = (k0 & 127) + q * 4;
            f32x4 v;
            if (gr < M) {
                if (sec == 0) {
                    v = *reinterpret_cast<const f32x4*>(&h[(size_t)gr * 128 + ks]);
                } else {
                    f32x4 a = *reinterpret_cast<const f32x4*>(&aggv[(size_t)gr * 128 + ks]);
                    #pragma unroll
                    for (int j = 0; j < 4; ++j) v[j] = fmaxf(a[j], 0.f);
                }
            } else {
                #pragma unroll
                for (int j = 0; j < 4; ++j) v[j] = 0.f;
            }
            short4v hh, ll;
            #pragma unroll
            for (int j = 0; j < 4; ++j) {
                hh[j] = f2bf(v[j]);
                ll[j] = f2bf(v[j] - bf2f(hh[j]));
            }
            *reinterpret_cast<short4v*>(&Ah[r][q * 4]) = hh;
            *reinterpret_cast<short4v*>(&Al[r][q * 4]) = ll;
        }
        #pragma unroll
        for (int i = 0; i < 4; ++i) {
            int idx = i * 256 + tid;
            int r = idx >> 3, q = idx & 7;
            short4v uu = *reinterpret_cast<const short4v*>(&BTh[(size_t)r * 256 + k0 + q * 4]);
            short4v ul = *reinterpret_cast<const short4v*>(&BTl[(size_t)r * 256 + k0 + q * 4]);
            *reinterpret_cast<short4v*>(&Bh[r][q * 4]) = uu;
            *reinterpret_cast<short4v*>(&Bl[r][q * 4]) = ul;
        }
        __syncthreads();
        bf16x8 afh[4], afl[4], bfh[4], bfl[4];
        #pragma unroll
        for (int mi = 0; mi < 4; ++mi) {
            afh[mi] = *reinterpret_cast<const bf16x8*>(&Ah[wr * 64 + mi * 16 + lr][lg * 8]);
            afl[mi] = *reinterpret_cast<const bf16x8*>(&Al[wr * 64 + mi * 16 + lr][lg * 8]);
        }
        #pragma unroll
        for (int ni = 0; ni < 4; ++ni) {
            bfh[ni] = *reinterpret_cast<const bf16x8*>(&Bh[wc * 64 + ni * 16 + lr][lg * 8]);
            bfl[ni] = *reinterpret_cast<const bf16x8*>(&Bl[wc * 64 + ni * 16 + lr][lg * 8]);
        }
        #pragma unroll
        for (int mi = 0; mi < 4; ++mi)
            #pragma unroll
            for (int ni = 0; ni < 4; ++ni) {
                acc[mi][ni] = __builtin_amdgcn_mfma_f32_16x16x32_bf16(afh[mi], bfh[ni], acc[mi][ni], 0, 0, 0);
                acc[mi][ni] = __builtin_amdgcn_mfma_f32_16x16x32_bf16(afl[mi], bfh[ni], acc[mi][ni], 0, 0, 0);
                acc[mi][ni] = __builtin_amdgcn_mfma_f32_16x16x32_bf16(afh[mi], bfl[ni], acc[mi][ni], 0, 0, 0);
            }
        __syncthreads();
    }

    #pragma unroll
    for (int mi = 0; mi < 4; ++mi) {
        #pragma unroll
        for (int ni = 0; ni < 4; ++ni) {
            int col = wc * 64 + ni * 16 + lr;
            float gbv = gb[col];
            #pragma unroll
            for (int r = 0; r < 4; ++r) {
                int row = row0 + wr * 64 + mi * 16 + lg * 4 + r;
                if (row >= M) continue;
                float beta = fmaxf(acc[mi][ni][r] + gbv, 0.f);
                float hv = h[(size_t)row * 128 + col];
                float hh = fmaxf(aggv[(size_t)row * 128 + col], 0.f);
                h[(size_t)row * 128 + col] = beta * hv + (1.f - beta) * hh;
            }
        }
    }
}

// ========== batch norm ==========
__global__ void bn_stats(const float* __restrict__ z, float* __restrict__ gsum,
                         float* __restrict__ gsq, int M) {
    int c = threadIdx.x & 127;
    int rr = threadIdx.x >> 7;
    float s = 0.f, q = 0.f;
    for (int r = blockIdx.x * 2 + rr; r < M; r += gridDim.x * 2) {
        float v = z[(size_t)r * 128 + c];
        s += v; q += v * v;
    }
    __shared__ float ls[256], lq[256];
    ls[threadIdx.x] = s; lq[threadIdx.x] = q;
    __syncthreads();
    if (threadIdx.x < 128) {
        atomicAdd(&gsum[c], ls[threadIdx.x] + ls[threadIdx.x + 128]);
        atomicAdd(&gsq[c],  lq[threadIdx.x] + lq[threadIdx.x + 128]);
    }
}

__global__ void bn_apply(float* __restrict__ z, const float* __restrict__ gsum,
                         const float* __restrict__ gsq, const float* __restrict__ g,
                         const float* __restrict__ b, int M) {
    size_t total = (size_t)M * 128;
    for (size_t idx = (size_t)blockIdx.x * 256 + threadIdx.x; idx < total;
         idx += (size_t)gridDim.x * 256) {
        int c = idx & 127;
        float mu = gsum[c] / (float)M;
        float var = gsq[c] / (float)M - mu * mu;
        float rs = rsqrtf(var + EPS);
        float v = (z[idx] - mu) * rs * g[c] + b[c];
        z[idx] = fmaxf(v, 0.f);
    }
}

__global__ void bn_stats_bf(const short* __restrict__ z, float* __restrict__ gsum,
                            float* __restrict__ gsq, int M) {
    int c = threadIdx.x & 127;
    int rr = threadIdx.x >> 7;
    float s = 0.f, q = 0.f;
    for (int r = blockIdx.x * 2 + rr; r < M; r += gridDim.x * 2) {
        float v = bf2f(z[(size_t)r * 128 + c]);
        s += v; q += v * v;
    }
    __shared__ float ls[256], lq[256];
    ls[threadIdx.x] = s; lq[threadIdx.x] = q;
    __syncthreads();
    if (threadIdx.x < 128) {
        atomicAdd(&gsum[c], ls[threadIdx.x] + ls[threadIdx.x + 128]);
        atomicAdd(&gsq[c],  lq[threadIdx.x] + lq[threadIdx.x + 128]);
    }
}

__global__ void bn_apply_bf(short* __restrict__ z, const float* __restrict__ gsum,
                            const float* __restrict__ gsq, const float* __restrict__ g,
                            const float* __restrict__ b, int M) {
    size_t total = (size_t)M * 128;
    for (size_t idx = (size_t)blockIdx.x * 256 + threadIdx.x; idx < total;
         idx += (size_t)gridDim.x * 256) {
        int c = idx & 127;
        float mu = gsum[c] / (float)M;
        float var = gsq[c] / (float)M - mu * mu;
        float rs = rsqrtf(var + EPS);
        float v = (bf2f(z[idx]) - mu) * rs * g[c] + b[c];
        z[idx] = f2bf(fmaxf(v, 0.f));
    }
}

// ========== prep ==========
__global__ void transpose_split(const float* __restrict__ in, short* __restrict__ outh,
                                short* __restrict__ outl, int K, int N) {
    int idx = blockIdx.x * 256 + threadIdx.x;
    if (idx >= K * N) return;
    int nI = idx / K, k = idx - nI * K;
    float v = in[(size_t)k * N + nI];
    short h = f2bf(v);
    outh[idx] = h;
    outl[idx] = f2bf(v - bf2f(h));
}

__global__ void cvt_f2b(const float* __restrict__ in, short* __restrict__ out, int n) {
    int i = blockIdx.x * 256 + threadIdx.x;
    if (i < n) out[i] = f2bf(in[i]);
}

__global__ void gate_combine_split(const float* __restrict__ gw, short* __restrict__ BTh,
                                   short* __restrict__ BTl) {
    int idx = blockIdx.x * 256 + threadIdx.x;
    if (idx >= 128 * 256) return;
    int n = idx >> 8, k = idx & 255;
    float v;
    if (k < 128) v = gw[(size_t)k * 128 + n] + gw[(size_t)(256 + k) * 128 + n];
    else {
        int kk = k - 128;
        v = gw[(size_t)(128 + kk) * 128 + n] - gw[(size_t)(256 + kk) * 128 + n];
    }
    short h = f2bf(v);
    BTh[idx] = h;
    BTl[idx] = f2bf(v - bf2f(h));
}

__global__ void build_wm(const float* __restrict__ wsrc, float* __restrict__ wm) {
    int idx = blockIdx.x * 256 + threadIdx.x;
    if (idx >= 128 * 128) return;
    int d = idx >> 7, c = idx & 127;
    float s = 0.f;
    #pragma unroll
    for (int h = 0; h < 8; ++h) s += wsrc[(size_t)d * 1024 + h * 128 + c];
    wm[idx] = s * 0.125f;
}

__global__ void perm_build(const int* __restrict__ ci, int* __restrict__ perm, int NF) {
    int i = blockIdx.x * 256 + threadIdx.x;
    if (i >= NF) return;
    int c = ci[i];
    if (i == 0 || ci[i - 1] != c) perm[c] = i;
}

__global__ void seg_pool(const float* __restrict__ fx, const int* __restrict__ perm,
                         float* __restrict__ pool, int F, int NF) {
    int idx = blockIdx.x * 256 + threadIdx.x;
    if (idx >= F * 128) return;
    int f = idx >> 7, c = idx & 127;
    int s = perm[f];
    int e = (f + 1 < F) ? perm[f + 1] : NF;
    float acc = 0.f;
    for (int i = s; i < e; ++i) acc += fx[(size_t)i * 128 + c];
    pool[idx] = fmaxf(acc, 0.f);
}

// ========== output ==========
__global__ __launch_bounds__(256) void out_phase1(const float* __restrict__ h,
                                                  const float* __restrict__ out_w,
                                                  const float* __restrict__ out_b,
                                                  const float* __restrict__ gat_bias,
                                                  float* __restrict__ out, int M) {
    int n = blockIdx.x * 4 + (threadIdx.x >> 6);
    if (n >= M) return;
    int l = threadIdx.x & 63;
    float p = fmaxf(h[(size_t)n * 128 + l], 0.f) * out_w[l]
            + fmaxf(h[(size_t)n * 128 + l + 64], 0.f) * out_w[l + 64];
    p += fmaxf(gat_bias[l], 0.f) * out_w[128 + l]
       + fmaxf(gat_bias[l + 64], 0.f) * out_w[128 + l + 64];
    #pragma unroll
    for (int off = 32; off; off >>= 1) p += __shfl_xor(p, off);
    if (l == 0) out[n] = p + out_b[0];
}

__global__ __launch_bounds__(256) void out_phase2(const float* __restrict__ fmv,
                                                  const int* __restrict__ perm,
                                                  const float* __restrict__ out_w,
                                                  const float* __restrict__ gat_bias,
                                                  float* __restrict__ out, int F) {
    int f = blockIdx.x * 4 + (threadIdx.x >> 6);
    if (f >= F) return;
    int l = threadIdx.x & 63;
    float p = fmv[(size_t)f * 128 + l] * out_w[128 + l]
            + fmv[(size_t)f * 128 + l + 64] * out_w[128 + l + 64];
    float b = fmaxf(gat_bias[l], 0.f) * out_w[128 + l]
            + fmaxf(gat_bias[l + 64], 0.f) * out_w[128 + l + 64];
    float d = p - b;
    #pragma unroll
    for (int off = 32; off; off >>= 1) d += __shfl_xor(d, off);
    if (l == 0) out[perm[f]] += d;
}

// ========== host ==========
extern "C" void kernel_launch(void* const* d_in, const int* in_sizes, int n_in,
                              void* d_out, int out_size, void* d_ws, size_t ws_size,
                              hipStream_t stream) {
    const int N = 50000, E = 100000, NF = 20000, EF = 40000, F = 10000;

    const float* x          = (const float*)d_in[0];
    const float* edge_attr  = (const float*)d_in[1];
    const float* frag_x     = (const float*)d_in[2];
    const float* frag_ea    = (const float*)d_in[3];
    const float* la_w = (const float*)d_in[4];
    const float* la_b = (const float*)d_in[5];
    const float* lb_w = (const float*)d_in[6];
    const float* lb_b = (const float*)d_in[7];
    const float* bn1_g = (const float*)d_in[8];
    const float* bn1_b = (const float*)d_in[9];
    const float* bn2_g = (const float*)d_in[10];
    const float* bn2_b = (const float*)d_in[11];
    const float* wn = (const float*)d_in[12];
    const float* wb = (const float*)d_in[13];
    const float* wl = (const float*)d_in[14];
    const float* wlb = (const float*)d_in[15];
    const float* gate_w = (const float*)d_in[16];
    const float* gate_b = (const float*)d_in[17];
    const float* gat_wsrc = (const float*)d_in[18];
    const float* gat_bias = (const float*)d_in[22];
    const float* out_w = (const float*)d_in[23];
    const float* out_b = (const float*)d_in[24];
    const int* edge_index = (const int*)d_in[25];
    const int* frag_edge_index = (const int*)d_in[26];
    const int* cluster_index = (const int*)d_in[27];

    char* p = (char*)d_ws;
    auto alloc = [&](size_t bytes) { char* r = p; p += (bytes + 255) & ~(size_t)255; return (void*)r; };
    float* hA    = (float*)alloc((size_t)N * 128 * 4);
    short* ea1   = (short*)alloc((size_t)E * 128 * 2);
    short* xph   = (short*)alloc((size_t)N * 128 * 2);
    short* xpl   = (short*)alloc((size_t)N * 128 * 2);
    short* ep    = (short*)alloc((size_t)E * 128 * 2);
    short* Y     = (short*)alloc((size_t)N * 1024 * 2);
    float* agg   = (float*)alloc((size_t)N * 128 * 4);
    float* ubuf  = (float*)alloc((size_t)N * 8 * 4);
    float* vbuf  = (float*)alloc((size_t)E * 8 * 4);
    short* la_wTh = (short*)alloc(128 * 128 * 2);
    short* la_wTl = (short*)alloc(128 * 128 * 2);
    short* lb_wTh = (short*)alloc(128 * 16 * 2);
    short* lb_wTl = (short*)alloc(128 * 16 * 2);
    short* wnTh   = (short*)alloc(3 * 128 * 128 * 2);
    short* wnTl   = (short*)alloc(3 * 128 * 128 * 2);
    short* wbH    = (short*)alloc(3 * 1024 * 128 * 2);
    short* gate2Th = (short*)alloc(128 * 256 * 2);
    short* gate2Tl = (short*)alloc(128 * 256 * 2);
    float* wmF    = (float*)alloc(128 * 128 * 4);
    short* wmTh   = (short*)alloc(128 * 128 * 2);
    short* wmTl   = (short*)alloc(128 * 128 * 2);
    float* stats  = (float*)alloc(256 * 4);
    char* yq = (char*)Y;
    float* fpool = (float*)yq;              yq += (size_t)F * 128 * 4;
    float* fmv   = (float*)yq;              yq += (size_t)F * 128 * 4;
    int*   perm  = (int*)yq;

    auto cdiv = [](int a, int b) { return (a + b - 1) / b; };

    // ---- weight prep ----
    transpose_split<<<cdiv(128 * 128, 256), 256, 0, stream>>>(la_w, la_wTh, la_wTl, 128, 128);
    transpose_split<<<cdiv(16 * 128, 256), 256, 0, stream>>>(lb_w, lb_wTh, lb_wTl, 16, 128);
    for (int l = 0; l < 3; ++l)
        transpose_split<<<cdiv(128 * 128, 256), 256, 0, stream>>>(
            wn + (size_t)l * 16384, wnTh + (size_t)l * 16384, wnTl + (size_t)l * 16384, 128, 128);
    cvt_f2b<<<cdiv(3 * 1024 * 128, 256), 256, 0, stream>>>(wb, wbH, 3 * 1024 * 128);
    gate_combine_split<<<cdiv(128 * 256, 256), 256, 0, stream>>>(gate_w, gate2Th, gate2Tl);
    build_wm<<<cdiv(128 * 128, 256), 256, 0, stream>>>(gat_wsrc, wmF);
    transpose_split<<<cdiv(128 * 128, 256), 256, 0, stream>>>(wmF, wmTh, wmTl, 128, 128);

    auto run_layer = [&](float* h, const short* ea_buf, const int* ei, int Mn, int Me, int layer) {
        const short* wnTh_l = wnTh + (size_t)layer * 16384;
        const short* wnTl_l = wnTl + (size_t)layer * 16384;
        const short* wb_l   = wbH + (size_t)layer * 131072;
        const float* wl_l   = wl + (size_t)layer * 384 * 8;
        const float* wlb_l  = wlb + (size_t)layer * 8;
        fused_xpy<<<cdiv(Mn, 128), 512, 0, stream>>>(h, wnTh_l, wnTl_l, wb_l, wl_l, xph, xpl, Y, Mn);
        gemm_bf16<0, 1><<<dim3(1, cdiv(Me, 128)), 256, 0, stream>>>(ea_buf, wnTh_l, nullptr, ep, Me, 128, 128);
        rowdot8<1><<<cdiv(Mn, 4), 256, 0, stream>>>(xph, xpl, wl_l + 256 * 8, wlb_l, ubuf, Mn);
        rowdot8<0><<<cdiv(Me, 4), 256, 0, stream>>>(ep, nullptr, wl_l + 128 * 8, nullptr, vbuf, Me);
        hipMemsetAsync(agg, 0, (size_t)Mn * 128 * 4, stream);
        edge_fused2<<<cdiv(Me, 4), 256, 0, stream>>>(xph, xpl, ep, Y, ei, ubuf, vbuf, agg, Me);
        gate_gemm_split<<<dim3(1, cdiv(Mn, 128)), 256, 0, stream>>>(h, agg, gate2Th, gate2Tl, gate_b, Mn);
    };

    // ---- atom path ----
    gemm_split<3, 0, 0><<<dim3(1, cdiv(N, 128)), 256, 0, stream>>>(x, la_wTh, la_wTl, la_b, hA, nullptr, N, 128, 128);
    hipMemsetAsync(stats, 0, 1024, stream);
    bn_stats<<<256, 256, 0, stream>>>(hA, stats, stats + 128, N);
    bn_apply<<<2048, 256, 0, stream>>>(hA, stats, stats + 128, bn1_g, bn1_b, N);

    gemm_split<3, 0, 1><<<dim3(1, cdiv(E, 128)), 256, 0, stream>>>(edge_attr, lb_wTh, lb_wTl, lb_b, ea1, nullptr, E, 128, 16);
    hipMemsetAsync(stats, 0, 1024, stream);
    bn_stats_bf<<<256, 256, 0, stream>>>(ea1, stats, stats + 128, E);
    bn_apply_bf<<<2048, 256, 0, stream>>>(ea1, stats, stats + 128, bn2_g, bn2_b, E);

    for (int l = 0; l < 3; ++l) run_layer(hA, ea1, edge_index, N, E, l);
    out_phase1<<<cdiv(N, 4), 256, 0, stream>>>(hA, out_w, out_b, gat_bias, (float*)d_out, N);

    // ---- fragment path ----
    gemm_split<3, 1, 0><<<dim3(1, cdiv(NF, 128)), 256, 0, stream>>>(frag_x, la_wTh, la_wTl, la_b, hA, nullptr, NF, 128, 128);

    gemm_split<3, 0, 1><<<dim3(1, cdiv(EF, 128)), 256, 0, stream>>>(frag_ea, lb_wTh, lb_wTl, lb_b, ea1, nullptr, EF, 128, 16);
    hipMemsetAsync(stats, 0, 1024, stream);
    bn_stats_bf<<<256, 256, 0, stream>>>(ea1, stats, stats + 128, EF);
    bn_apply_bf<<<2048, 256, 0, stream>>>(ea1, stats, stats + 128, bn2_g, bn2_b, EF);

    for (int l = 0; l < 3; ++l) run_layer(hA, ea1, frag_edge_index, NF, EF, l);

    perm_build<<<cdiv(NF, 256), 256, 0, stream>>>(cluster_index, perm, NF);
    seg_pool<<<cdiv(F * 128, 256), 256, 0, stream>>>(hA, perm, fpool, F, NF);
    gemm_split<3, 1, 0><<<dim3(1, cdiv(F, 128)), 256, 0, stream>>>(fpool, wmTh, wmTl, gat_bias, fmv, nullptr, F, 128, 128);
    out_phase2<<<cdiv(F, 4), 256, 0, stream>>>(fmv, perm, out_w, gat_bias, (float*)d_out, F);
}